// Round 1
// baseline (330.498 us; speedup 1.0000x reference)
//
#include <hip/hip_runtime.h>
#include <stdint.h>

#define D_MODEL 1024
#define NH 16
#define HD 64
#define SEQ 2048
#define BATCH 2
#define ROWS (BATCH * SEQ)   // 4096
#define KDIM 1024
#define NQKV 3072

typedef unsigned short u16;
typedef short bf16x8 __attribute__((ext_vector_type(8)));   // 8 bf16 in 4 VGPRs
typedef float f32x4 __attribute__((ext_vector_type(4)));

__device__ __forceinline__ u16 f2bf(float f) {
  union { float f; unsigned u; } x; x.f = f;
  unsigned r = x.u + 0x7fff + ((x.u >> 16) & 1);   // RNE
  return (u16)(r >> 16);
}
__device__ __forceinline__ float bf2f(u16 h) {
  union { unsigned u; float f; } x; x.u = ((unsigned)h) << 16;
  return x.f;
}

// async global->LDS, 16B per lane. LDS dst must be wave-uniform base + lane*16.
__device__ __forceinline__ void gload16(const u16* g, u16* l) {
  __builtin_amdgcn_global_load_lds(
      (const __attribute__((address_space(1))) unsigned int*)g,
      (__attribute__((address_space(3))) unsigned int*)l, 16, 0, 0);
}

// ---------------- fp32 -> bf16 flat convert (float4 / ushort4) ----------------
__global__ void convert_f32_bf16(const float* __restrict__ in, u16* __restrict__ out, int n4) {
  int i = blockIdx.x * blockDim.x + threadIdx.x;
  if (i >= n4) return;
  float4 v = ((const float4*)in)[i];
  ushort4 o;
  o.x = f2bf(v.x); o.y = f2bf(v.y); o.z = f2bf(v.z); o.w = f2bf(v.w);
  ((ushort4*)out)[i] = o;
}

// ---------------- transpose + convert: W (K x N) fp32 -> Wt (N x K) bf16 ------
__global__ void transpose_bf16(const float* __restrict__ W, u16* __restrict__ Wt, int K, int N) {
  __shared__ float tile[32][33];
  int c0 = blockIdx.x * 32, r0 = blockIdx.y * 32;
  int tx = threadIdx.x, ty = threadIdx.y;   // (32, 8)
  for (int i = ty; i < 32; i += 8)
    tile[i][tx] = W[(size_t)(r0 + i) * N + c0 + tx];
  __syncthreads();
  for (int i = ty; i < 32; i += 8)
    Wt[(size_t)(c0 + i) * K + r0 + tx] = f2bf(tile[tx][i]);
}

// ---------------- QKV GEMM: (4096x1024) @ (1024x3072) + bias ----------------
// A row-major bf16, Bt = W^T (3072x1024) bf16. 128x128x64 tiles, 4 waves of 64x64.
// Epilogue scatters to q,k as (b,h,s,hd) and v TRANSPOSED as (b,h,hd,s).
__global__ __launch_bounds__(256) void qkv_gemm_kernel(
    const u16* __restrict__ A, const u16* __restrict__ Bt, const float* __restrict__ bias,
    u16* __restrict__ qb, u16* __restrict__ kb, u16* __restrict__ vtb) {
  __shared__ u16 As[128 * 64];
  __shared__ u16 Bs[128 * 64];
  const int tid = threadIdx.x;
  const int lane = tid & 63, wave = tid >> 6;
  const int wr = (wave >> 1) << 6, wc = (wave & 1) << 6;
  const int lrow = lane & 15, quad = lane >> 4;
  const int lk = quad * 8;
  const int rowA0 = blockIdx.y * 128, rowB0 = blockIdx.x * 128;

  f32x4 acc[4][4] = {};

  for (int k0 = 0; k0 < KDIM; k0 += 64) {
    __syncthreads();
#pragma unroll
    for (int it = 0; it < 4; ++it) {
      int flat = it * 256 + tid;
      int r = flat >> 3, c = (flat & 7) << 3;
      gload16(A + (size_t)(rowA0 + r) * KDIM + k0 + c, As + flat * 8);
      gload16(Bt + (size_t)(rowB0 + r) * KDIM + k0 + c, Bs + flat * 8);
    }
    __syncthreads();
#pragma unroll
    for (int kk = 0; kk < 64; kk += 32) {
      bf16x8 af[4], bfr[4];
#pragma unroll
      for (int mi = 0; mi < 4; ++mi)
        af[mi] = *(const bf16x8*)(As + (wr + mi * 16 + lrow) * 64 + kk + lk);
#pragma unroll
      for (int ni = 0; ni < 4; ++ni)
        bfr[ni] = *(const bf16x8*)(Bs + (wc + ni * 16 + lrow) * 64 + kk + lk);
#pragma unroll
      for (int mi = 0; mi < 4; ++mi)
#pragma unroll
        for (int ni = 0; ni < 4; ++ni)
          acc[mi][ni] = __builtin_amdgcn_mfma_f32_16x16x32_bf16(af[mi], bfr[ni], acc[mi][ni], 0, 0, 0);
    }
  }

#pragma unroll
  for (int ni = 0; ni < 4; ++ni) {
    int col = rowB0 + wc + ni * 16 + lrow;          // 0..3071
    float bv = bias[col];
    int which = col >> 10, rem = col & 1023;
    int h = rem >> 6, hd = rem & 63;
#pragma unroll
    for (int mi = 0; mi < 4; ++mi) {
#pragma unroll
      for (int r = 0; r < 4; ++r) {
        int row = rowA0 + wr + mi * 16 + quad * 4 + r;   // 0..4095
        int b = row >> 11, s = row & 2047;
        u16 val = f2bf(acc[mi][ni][r] + bv);
        int bh = b * NH + h;
        if (which == 0)      qb[((size_t)bh * SEQ + s) * HD + hd] = val;
        else if (which == 1) kb[((size_t)bh * SEQ + s) * HD + hd] = val;
        else                 vtb[((size_t)bh * HD + hd) * SEQ + s] = val;
      }
    }
  }
}

// ---------------- RoPE in-place on q,k (bf16, layout (bh, s, hd)) -------------
__global__ void rope_kernel(u16* __restrict__ qb, u16* __restrict__ kb) {
  int idx = blockIdx.x * 256 + threadIdx.x;   // 2*32*2048*32 = 4194304 threads
  int i = idx & 31;
  int s = (idx >> 5) & 2047;
  int bh = (idx >> 16) & 31;
  int buf = idx >> 21;
  u16* p = (buf ? kb : qb) + ((size_t)bh * SEQ + s) * HD;
  float x1 = bf2f(p[i]), x2 = bf2f(p[i + 32]);
  float inv = __expf(-(float)i * 0.28782313662425572f);  // ln(10000)/32
  float ang = (float)s * inv;
  float sn = __sinf(ang), cs = __cosf(ang);
  p[i]      = f2bf(x1 * cs - x2 * sn);
  p[i + 32] = f2bf(x2 * cs + x1 * sn);
}

// ---------------- causal flash attention ----------------
// grid (16 qtiles [swizzled], 32 bh). 4 waves: wave w owns q-rows w*32..w*32+31.
__global__ __launch_bounds__(256, 2) void flash_kernel(
    const u16* __restrict__ qb, const u16* __restrict__ kb,
    const u16* __restrict__ vtb, u16* __restrict__ attnb) {
  __shared__ u16 Qs[128 * 64];    // 16 KB
  __shared__ u16 Ks[128 * 64];    // 16 KB
  __shared__ u16 Vts[64 * 128];   // 16 KB  (hd x key)
  __shared__ u16 Ps[128 * 128];   // 32 KB  (qrow x key), per-wave 32-row slices

  const int tid = threadIdx.x, lane = tid & 63, wave = tid >> 6;
  const int lrow = lane & 15, quad = lane >> 4;
  int j = blockIdx.x;
  int qi = (j & 1) ? (j >> 1) : (15 - (j >> 1));   // balance causal triangle
  const int bh = blockIdx.y;
  const int b = bh >> 4, h = bh & 15;

  const u16* qp = qb + (size_t)bh * SEQ * HD;
  const u16* kp = kb + (size_t)bh * SEQ * HD;
  const u16* vp = vtb + (size_t)bh * HD * SEQ;

#pragma unroll
  for (int it = 0; it < 4; ++it) {      // stage Q tile once
    int flat = it * 256 + tid;
    int r = flat >> 3, c = (flat & 7) << 3;
    gload16(qp + (size_t)(qi * 128 + r) * HD + c, Qs + flat * 8);
  }

  float m_i[2][4], l_i[2][4];
  f32x4 oacc[2][4] = {};
#pragma unroll
  for (int mi = 0; mi < 2; ++mi)
#pragma unroll
    for (int r = 0; r < 4; ++r) { m_i[mi][r] = -__builtin_inff(); l_i[mi][r] = 0.f; }

  const float kS = 0.18033688011112042f;   // log2(e) / sqrt(64)

  for (int kt = 0; kt <= qi; ++kt) {
    __syncthreads();   // everyone done with previous K/V tiles (drains Q loads on iter 0)
#pragma unroll
    for (int it = 0; it < 4; ++it) {
      int flat = it * 256 + tid;
      int r = flat >> 3, c = (flat & 7) << 3;
      gload16(kp + (size_t)(kt * 128 + r) * HD + c, Ks + flat * 8);
      int rv = flat >> 4, cv = (flat & 15) << 3;
      gload16(vp + (size_t)rv * SEQ + kt * 128 + cv, Vts + flat * 8);
    }
    __syncthreads();

    // S = Q K^T for this wave's 32 rows x 128 keys
    f32x4 sc[2][8] = {};
#pragma unroll
    for (int kk = 0; kk < 64; kk += 32) {
      bf16x8 aq[2], bk[8];
#pragma unroll
      for (int mi = 0; mi < 2; ++mi)
        aq[mi] = *(const bf16x8*)(Qs + (wave * 32 + mi * 16 + lrow) * 64 + kk + quad * 8);
#pragma unroll
      for (int ni = 0; ni < 8; ++ni)
        bk[ni] = *(const bf16x8*)(Ks + (ni * 16 + lrow) * 64 + kk + quad * 8);
#pragma unroll
      for (int mi = 0; mi < 2; ++mi)
#pragma unroll
        for (int ni = 0; ni < 8; ++ni)
          sc[mi][ni] = __builtin_amdgcn_mfma_f32_16x16x32_bf16(aq[mi], bk[ni], sc[mi][ni], 0, 0, 0);
    }

    if (kt == qi) {   // diagonal tile: causal mask (raw-score domain)
#pragma unroll
      for (int mi = 0; mi < 2; ++mi)
#pragma unroll
        for (int ni = 0; ni < 8; ++ni)
#pragma unroll
          for (int r = 0; r < 4; ++r) {
            int rl = wave * 32 + mi * 16 + quad * 4 + r;
            int cl = ni * 16 + lrow;
            if (cl > rl) sc[mi][ni][r] = -1e30f;
          }
    }

    // online softmax (exp2 domain, scale folded into exponent)
#pragma unroll
    for (int mi = 0; mi < 2; ++mi) {
#pragma unroll
      for (int r = 0; r < 4; ++r) {
        float mx = -__builtin_inff();
#pragma unroll
        for (int ni = 0; ni < 8; ++ni) mx = fmaxf(mx, sc[mi][ni][r]);
        for (int off = 8; off > 0; off >>= 1) mx = fmaxf(mx, __shfl_xor(mx, off, 16));
        float mold = m_i[mi][r];
        float mnew = fmaxf(mold, mx);
        float al = exp2f((mold - mnew) * kS);
        float sum = 0.f;
#pragma unroll
        for (int ni = 0; ni < 8; ++ni) {
          float p = exp2f((sc[mi][ni][r] - mnew) * kS);
          sc[mi][ni][r] = p;
          sum += p;
        }
        for (int off = 8; off > 0; off >>= 1) sum += __shfl_xor(sum, off, 16);
        l_i[mi][r] = l_i[mi][r] * al + sum;
        m_i[mi][r] = mnew;
#pragma unroll
        for (int n4 = 0; n4 < 4; ++n4) oacc[mi][n4][r] *= al;
      }
    }

    // P: C-layout regs -> LDS row-major (A-operand layout for PV)
#pragma unroll
    for (int mi = 0; mi < 2; ++mi)
#pragma unroll
      for (int ni = 0; ni < 8; ++ni)
#pragma unroll
        for (int r = 0; r < 4; ++r)
          Ps[(wave * 32 + mi * 16 + quad * 4 + r) * 128 + ni * 16 + lrow] = f2bf(sc[mi][ni][r]);
    asm volatile("s_waitcnt lgkmcnt(0)" ::: "memory");

    // O += P @ V  (keys in chunks of 32)
#pragma unroll
    for (int kc = 0; kc < 4; ++kc) {
      bf16x8 ap[2], bv[4];
#pragma unroll
      for (int mi = 0; mi < 2; ++mi)
        ap[mi] = *(const bf16x8*)(Ps + (wave * 32 + mi * 16 + lrow) * 128 + kc * 32 + quad * 8);
#pragma unroll
      for (int ni = 0; ni < 4; ++ni)
        bv[ni] = *(const bf16x8*)(Vts + (ni * 16 + lrow) * 128 + kc * 32 + quad * 8);
#pragma unroll
      for (int mi = 0; mi < 2; ++mi)
#pragma unroll
        for (int ni = 0; ni < 4; ++ni)
          oacc[mi][ni] = __builtin_amdgcn_mfma_f32_16x16x32_bf16(ap[mi], bv[ni], oacc[mi][ni], 0, 0, 0);
    }
  }

  // epilogue: O / l -> attn buffer (B,S,D) bf16
#pragma unroll
  for (int mi = 0; mi < 2; ++mi) {
#pragma unroll
    for (int r = 0; r < 4; ++r) {
      float rl = 1.f / l_i[mi][r];
      int srow = qi * 128 + wave * 32 + mi * 16 + quad * 4 + r;
#pragma unroll
      for (int ni = 0; ni < 4; ++ni)
        attnb[(size_t)(b * SEQ + srow) * D_MODEL + h * HD + ni * 16 + lrow] =
            f2bf(oacc[mi][ni][r] * rl);
    }
  }
}

// ---------------- output projection: (4096x1024) @ (1024x1024) + bias -> fp32 --
__global__ __launch_bounds__(256) void out_gemm_kernel(
    const u16* __restrict__ A, const u16* __restrict__ Bt, const float* __restrict__ bias,
    float* __restrict__ out) {
  __shared__ u16 As[128 * 64];
  __shared__ u16 Bs[128 * 64];
  const int tid = threadIdx.x;
  const int lane = tid & 63, wave = tid >> 6;
  const int wr = (wave >> 1) << 6, wc = (wave & 1) << 6;
  const int lrow = lane & 15, quad = lane >> 4;
  const int lk = quad * 8;
  const int rowA0 = blockIdx.y * 128, rowB0 = blockIdx.x * 128;

  f32x4 acc[4][4] = {};

  for (int k0 = 0; k0 < KDIM; k0 += 64) {
    __syncthreads();
#pragma unroll
    for (int it = 0; it < 4; ++it) {
      int flat = it * 256 + tid;
      int r = flat >> 3, c = (flat & 7) << 3;
      gload16(A + (size_t)(rowA0 + r) * KDIM + k0 + c, As + flat * 8);
      gload16(Bt + (size_t)(rowB0 + r) * KDIM + k0 + c, Bs + flat * 8);
    }
    __syncthreads();
#pragma unroll
    for (int kk = 0; kk < 64; kk += 32) {
      bf16x8 af[4], bfr[4];
#pragma unroll
      for (int mi = 0; mi < 4; ++mi)
        af[mi] = *(const bf16x8*)(As + (wr + mi * 16 + lrow) * 64 + kk + lk);
#pragma unroll
      for (int ni = 0; ni < 4; ++ni)
        bfr[ni] = *(const bf16x8*)(Bs + (wc + ni * 16 + lrow) * 64 + kk + lk);
#pragma unroll
      for (int mi = 0; mi < 4; ++mi)
#pragma unroll
        for (int ni = 0; ni < 4; ++ni)
          acc[mi][ni] = __builtin_amdgcn_mfma_f32_16x16x32_bf16(af[mi], bfr[ni], acc[mi][ni], 0, 0, 0);
    }
  }

#pragma unroll
  for (int ni = 0; ni < 4; ++ni) {
    int col = rowB0 + wc + ni * 16 + lrow;
    float bv = bias[col];
#pragma unroll
    for (int mi = 0; mi < 4; ++mi)
#pragma unroll
      for (int r = 0; r < 4; ++r) {
        int row = rowA0 + wr + mi * 16 + quad * 4 + r;
        out[(size_t)row * D_MODEL + col] = acc[mi][ni][r] + bv;
      }
  }
}

extern "C" void kernel_launch(void* const* d_in, const int* in_sizes, int n_in,
                              void* d_out, int out_size, void* d_ws, size_t ws_size,
                              hipStream_t stream) {
  const float* query = (const float*)d_in[0];
  const float* W_qkv = (const float*)d_in[1];
  const float* b_qkv = (const float*)d_in[2];
  const float* W_out = (const float*)d_in[3];
  const float* b_out = (const float*)d_in[4];
  float* out = (float*)d_out;

  char* ws = (char*)d_ws;
  u16* q_bf   = (u16*)(ws);                 //  8 MB  query bf16 (4096x1024)
  u16* wt_qkv = (u16*)(ws + 8388608);       //  6 MB  W_qkv^T bf16 (3072x1024)
  u16* wt_out = (u16*)(ws + 14680064);      //  2 MB  W_out^T bf16 (1024x1024)
  u16* qbuf   = (u16*)(ws + 16777216);      //  8 MB  q (bh,s,hd)
  u16* kbuf   = (u16*)(ws + 25165824);      //  8 MB  k (bh,s,hd)
  u16* vtbuf  = (u16*)(ws + 33554432);      //  8 MB  v^T (bh,hd,s)
  u16* attnb  = (u16*)(ws + 41943040);      //  8 MB  attn (B,S,D) bf16

  convert_f32_bf16<<<dim3(4096), dim3(256), 0, stream>>>(query, q_bf, ROWS * KDIM / 4);
  transpose_bf16<<<dim3(NQKV / 32, KDIM / 32), dim3(32, 8), 0, stream>>>(W_qkv, wt_qkv, KDIM, NQKV);
  transpose_bf16<<<dim3(D_MODEL / 32, KDIM / 32), dim3(32, 8), 0, stream>>>(W_out, wt_out, KDIM, D_MODEL);
  qkv_gemm_kernel<<<dim3(NQKV / 128, ROWS / 128), dim3(256), 0, stream>>>(q_bf, wt_qkv, b_qkv, qbuf, kbuf, vtbuf);
  rope_kernel<<<dim3(4194304 / 256), dim3(256), 0, stream>>>(qbuf, kbuf);
  flash_kernel<<<dim3(16, 32), dim3(256), 0, stream>>>(qbuf, kbuf, vtbuf, attnb);
  out_gemm_kernel<<<dim3(D_MODEL / 128, ROWS / 128), dim3(256), 0, stream>>>(attnb, wt_out, b_out, out);
}

// Round 2
// 218.952 us; speedup vs baseline: 1.5095x; 1.5095x over previous
//
#include <hip/hip_runtime.h>
#include <stdint.h>

#define D_MODEL 1024
#define NH 16
#define HD 64
#define SEQ 2048
#define BATCH 2
#define ROWS (BATCH * SEQ)   // 4096
#define KDIM 1024
#define NQKV 3072

typedef unsigned short u16;
typedef short bf16x8 __attribute__((ext_vector_type(8)));   // 8 bf16 in 4 VGPRs
typedef short bf16x4 __attribute__((ext_vector_type(4)));   // 4 bf16 in 2 VGPRs
typedef float f32x4 __attribute__((ext_vector_type(4)));

__device__ __forceinline__ u16 f2bf(float f) {
  union { float f; unsigned u; } x; x.f = f;
  unsigned r = x.u + 0x7fff + ((x.u >> 16) & 1);   // RNE
  return (u16)(r >> 16);
}

// K=16 bf16 MFMA: prefer native 16x16x16; else zero-padded K=32 (identical result).
#ifndef HAVE_MFMA16_1K
#if defined(__has_builtin)
#if __has_builtin(__builtin_amdgcn_mfma_f32_16x16x16bf16_1k)
#define HAVE_MFMA16_1K 1
#endif
#endif
#endif
__device__ __forceinline__ f32x4 mfma16(bf16x4 a, bf16x4 b, f32x4 c) {
#ifdef HAVE_MFMA16_1K
  return __builtin_amdgcn_mfma_f32_16x16x16bf16_1k(a, b, c, 0, 0, 0);
#else
  bf16x8 a8 = {a[0], a[1], a[2], a[3], 0, 0, 0, 0};
  bf16x8 b8 = {b[0], b[1], b[2], b[3], 0, 0, 0, 0};
  return __builtin_amdgcn_mfma_f32_16x16x32_bf16(a8, b8, c, 0, 0, 0);
#endif
}

// async global->LDS, 16B per lane. LDS dst must be wave-uniform base + lane*16.
__device__ __forceinline__ void gload16(const u16* g, u16* l) {
  __builtin_amdgcn_global_load_lds(
      (const __attribute__((address_space(1))) unsigned int*)g,
      (__attribute__((address_space(3))) unsigned int*)l, 16, 0, 0);
}

// ---------------- fp32 -> bf16 flat convert ----------------
__global__ void convert_f32_bf16(const float* __restrict__ in, u16* __restrict__ out, int n4) {
  int i = blockIdx.x * blockDim.x + threadIdx.x;
  if (i >= n4) return;
  float4 v = ((const float4*)in)[i];
  ushort4 o;
  o.x = f2bf(v.x); o.y = f2bf(v.y); o.z = f2bf(v.z); o.w = f2bf(v.w);
  ((ushort4*)out)[i] = o;
}

// ---------------- transpose + convert: W (K x N) fp32 -> Wt (N x K) bf16 ------
__global__ void transpose_bf16(const float* __restrict__ W, u16* __restrict__ Wt, int K, int N) {
  __shared__ float tile[32][33];
  int c0 = blockIdx.x * 32, r0 = blockIdx.y * 32;
  int tx = threadIdx.x, ty = threadIdx.y;   // (32, 8)
  for (int i = ty; i < 32; i += 8)
    tile[i][tx] = W[(size_t)(r0 + i) * N + c0 + tx];
  __syncthreads();
  for (int i = ty; i < 32; i += 8)
    Wt[(size_t)(c0 + i) * K + r0 + tx] = f2bf(tile[tx][i]);
}

// ---------------- QKV GEMM + bias + fused RoPE + swizzled scatter ----------------
// q/k layout: qb[bh][s][pos], pos = ((hd>>3) ^ (s&7))*8 + (hd&7)   (bank-swizzled)
// v layout:   vtb[bh][hd][ (s>>7)*128 + ((((s>>2)&31) ^ (hd&15))<<2) + (s&3) ]
__global__ __launch_bounds__(256) void qkv_gemm_kernel(
    const u16* __restrict__ A, const u16* __restrict__ Bt, const float* __restrict__ bias,
    u16* __restrict__ qb, u16* __restrict__ kb, u16* __restrict__ vtb) {
  __shared__ u16 As[128 * 64];
  __shared__ u16 Bs[128 * 64];
  const int tid = threadIdx.x;
  const int lane = tid & 63, wave = tid >> 6;
  const int wr = (wave >> 1) << 6, wc = (wave & 1) << 6;
  const int lrow = lane & 15, quad = lane >> 4;
  const int lk = quad * 8;
  const int rowA0 = blockIdx.y * 128, rowB0 = blockIdx.x * 128;

  f32x4 acc[4][4] = {};

  for (int k0 = 0; k0 < KDIM; k0 += 64) {
    __syncthreads();
#pragma unroll
    for (int it = 0; it < 4; ++it) {
      int flat = it * 256 + tid;
      int r = flat >> 3, c = (flat & 7) << 3;
      gload16(A + (size_t)(rowA0 + r) * KDIM + k0 + c, As + flat * 8);
      gload16(Bt + (size_t)(rowB0 + r) * KDIM + k0 + c, Bs + flat * 8);
    }
    __syncthreads();
#pragma unroll
    for (int kk = 0; kk < 64; kk += 32) {
      bf16x8 af[4], bfr[4];
#pragma unroll
      for (int mi = 0; mi < 4; ++mi)
        af[mi] = *(const bf16x8*)(As + (wr + mi * 16 + lrow) * 64 + kk + lk);
#pragma unroll
      for (int ni = 0; ni < 4; ++ni)
        bfr[ni] = *(const bf16x8*)(Bs + (wc + ni * 16 + lrow) * 64 + kk + lk);
#pragma unroll
      for (int mi = 0; mi < 4; ++mi)
#pragma unroll
        for (int ni = 0; ni < 4; ++ni)
          acc[mi][ni] = __builtin_amdgcn_mfma_f32_16x16x32_bf16(af[mi], bfr[ni], acc[mi][ni], 0, 0, 0);
    }
  }

  const int col0 = rowB0 + wc;             // 64-aligned -> single head per 64-col slab
  const int which = col0 >> 10;            // 0=q 1=k 2=v (uniform)
  const int h = (col0 & 1023) >> 6;        // uniform

#pragma unroll
  for (int ni = 0; ni < 4; ++ni) {
    float bv = bias[col0 + ni * 16 + lrow];
#pragma unroll
    for (int mi = 0; mi < 4; ++mi)
#pragma unroll
      for (int r = 0; r < 4; ++r) acc[mi][ni][r] += bv;
  }

  if (which < 2) {   // fused RoPE: pairs (hd, hd+32) = (ni, ni+2), same lane
#pragma unroll
    for (int p = 0; p < 2; ++p) {
      float inv = __expf(-(float)(p * 16 + lrow) * 0.28782313662425572f); // ln(1e4)/32
#pragma unroll
      for (int mi = 0; mi < 4; ++mi)
#pragma unroll
        for (int r = 0; r < 4; ++r) {
          int row = rowA0 + wr + mi * 16 + quad * 4 + r;
          float ang = (float)(row & 2047) * inv;
          float sn = __sinf(ang), cs = __cosf(ang);
          float x1 = acc[mi][p][r], x2 = acc[mi][p + 2][r];
          acc[mi][p][r]     = x1 * cs - x2 * sn;
          acc[mi][p + 2][r] = x2 * cs + x1 * sn;
        }
    }
  }

  u16* outqk = (which == 0) ? qb : kb;
#pragma unroll
  for (int ni = 0; ni < 4; ++ni) {
    int hd = ni * 16 + lrow;
#pragma unroll
    for (int mi = 0; mi < 4; ++mi)
#pragma unroll
      for (int r = 0; r < 4; ++r) {
        int row = rowA0 + wr + mi * 16 + quad * 4 + r;
        int bb = row >> 11, s = row & 2047;
        u16 val = f2bf(acc[mi][ni][r]);
        int bhh = bb * NH + h;
        if (which < 2) {
          int pos = (((hd >> 3) ^ (s & 7)) << 3) | (hd & 7);
          outqk[((size_t)bhh * SEQ + s) * HD + pos] = val;
        } else {
          int posl = ((((s >> 2) & 31) ^ (hd & 15)) << 2) | (s & 3);
          vtb[((size_t)bhh * HD + hd) * SEQ + ((s >> 7) << 7) + posl] = val;
        }
      }
  }
}

// ---------------- causal flash attention v2 (S^T formulation) ----------------
// 512 uniform blocks: block processes q-tiles (pair, 31-pair), 64 rows each ->
// exactly 17 kt-iterations per block. Wave w owns q rows tile*64+w*16..+15;
// lane's q = lrow (softmax stats per-lane, no cross-q shuffles for rescale).
// K/V double-buffered, one barrier per iter, async global_load_lds prefetch.
__global__ __launch_bounds__(256, 2) void flash_kernel(
    const u16* __restrict__ qb, const u16* __restrict__ kb,
    const u16* __restrict__ vtb, u16* __restrict__ attnb) {
  __shared__ u16 Qs[64 * 64];          //  8 KB
  __shared__ u16 Ks[2][128 * 64];      // 32 KB
  __shared__ u16 Vts[2][64 * 128];     // 32 KB   -> 72 KB total, 2 blocks/CU

  const int tid = threadIdx.x, lane = tid & 63, wave = tid >> 6;
  const int lrow = lane & 15, quad = lane >> 4;
  const int id = blockIdx.x;
  const int bh = (id & 7) * 4 + ((id >> 3) & 3);   // XCD-local bh grouping
  const int pair = id >> 5;
  const int b = bh >> 4, h = bh & 15;

  const u16* qp = qb + (size_t)bh * SEQ * HD;
  const u16* kp = kb + (size_t)bh * SEQ * HD;
  const u16* vp = vtb + (size_t)bh * HD * SEQ;

  const float kS = 0.18033688011112042f;   // log2(e)/sqrt(64)

  for (int tsel = 0; tsel < 2; ++tsel) {
    const int tile = tsel ? (31 - pair) : pair;
    __syncthreads();   // prior tile's LDS reads done before restage
#pragma unroll
    for (int it = 0; it < 2; ++it) {     // stage Q (64x64)
      int flat = it * 256 + tid;
      gload16(qp + (size_t)(tile * 64 + (flat >> 3)) * HD + ((flat & 7) << 3), Qs + flat * 8);
    }
#pragma unroll
    for (int it = 0; it < 4; ++it) {     // stage K/V tile 0 into buf 0
      int flat = it * 256 + tid;
      gload16(kp + (size_t)(flat >> 3) * HD + ((flat & 7) << 3), Ks[0] + flat * 8);
      gload16(vp + (size_t)(flat >> 4) * SEQ + ((flat & 15) << 3), Vts[0] + flat * 8);
    }

    float m_i = -3.0e38f, l_i = 0.f;
    f32x4 oacc[4] = {};
    const int kmax = (tile * 64 + 63) >> 7;
    const int qg = tile * 64 + wave * 16 + lrow;
    const int sw8 = (lrow & 7);

    for (int kt = 0; kt <= kmax; ++kt) {
      const int cur = kt & 1, nxt = cur ^ 1;
      __syncthreads();   // drains cur's staging; separates LDS buffer reuse
      if (kt < kmax) {   // async prefetch next K/V — overlaps entire compute
#pragma unroll
        for (int it = 0; it < 4; ++it) {
          int flat = it * 256 + tid;
          gload16(kp + (size_t)((kt + 1) * 128 + (flat >> 3)) * HD + ((flat & 7) << 3),
                  Ks[nxt] + flat * 8);
          gload16(vp + (size_t)(flat >> 4) * SEQ + (kt + 1) * 128 + ((flat & 15) << 3),
                  Vts[nxt] + flat * 8);
        }
      }

      // S^T = K·Q^T : lane holds S^T[key=ki*16+quad*4+r][q=qg]
      f32x4 sc[8] = {};
#pragma unroll
      for (int hc = 0; hc < 2; ++hc) {
        bf16x8 bq = *(const bf16x8*)(Qs + (wave * 16 + lrow) * 64 + (((hc * 4 + quad) ^ sw8) << 3));
#pragma unroll
        for (int ki = 0; ki < 8; ++ki) {
          bf16x8 ak = *(const bf16x8*)(Ks[cur] + (ki * 16 + lrow) * 64 + (((hc * 4 + quad) ^ sw8) << 3));
          sc[ki] = __builtin_amdgcn_mfma_f32_16x16x32_bf16(ak, bq, sc[ki], 0, 0, 0);
        }
      }

      if (kt == kmax) {   // causal mask on the diagonal-containing tile
#pragma unroll
        for (int ki = 0; ki < 8; ++ki)
#pragma unroll
          for (int r = 0; r < 4; ++r)
            if (kt * 128 + ki * 16 + quad * 4 + r > qg) sc[ki][r] = -1e30f;
      }

      // online softmax for q=qg: 32 in-lane values + 2 shfls across quads
      float mx = sc[0][0];
#pragma unroll
      for (int ki = 0; ki < 8; ++ki)
#pragma unroll
        for (int r = 0; r < 4; ++r) mx = fmaxf(mx, sc[ki][r]);
      mx = fmaxf(mx, __shfl_xor(mx, 16));
      mx = fmaxf(mx, __shfl_xor(mx, 32));
      float mnew = fmaxf(m_i, mx);
      float al = exp2f((m_i - mnew) * kS);
      float sum = 0.f;
#pragma unroll
      for (int ki = 0; ki < 8; ++ki)
#pragma unroll
        for (int r = 0; r < 4; ++r) {
          float p = exp2f((sc[ki][r] - mnew) * kS);
          sc[ki][r] = p;
          sum += p;
        }
      sum += __shfl_xor(sum, 16);
      sum += __shfl_xor(sum, 32);
      l_i = l_i * al + sum;
      m_i = mnew;
#pragma unroll
      for (int mi = 0; mi < 4; ++mi) oacc[mi] *= al;

      // P^T fragments: C-layout rows(=keys) ARE the K=16 B-fragment k-layout
      bf16x4 pf[8];
#pragma unroll
      for (int ki = 0; ki < 8; ++ki) {
        bf16x4 t;
        t[0] = (short)f2bf(sc[ki][0]); t[1] = (short)f2bf(sc[ki][1]);
        t[2] = (short)f2bf(sc[ki][2]); t[3] = (short)f2bf(sc[ki][3]);
        pf[ki] = t;
      }

      // O^T += V^T · P^T  (A-frag: 4 consecutive swizzled keys from Vts)
#pragma unroll
      for (int mi = 0; mi < 4; ++mi)
#pragma unroll
        for (int ki = 0; ki < 8; ++ki) {
          bf16x4 av = *(const bf16x4*)(Vts[cur] + (mi * 16 + lrow) * 128 +
                                       (((ki * 4 + quad) ^ lrow) << 2));
          oacc[mi] = mfma16(av, pf[ki], oacc[mi]);
        }
    }

    // epilogue: lane's regs all belong to q=qg -> scale by its own 1/l
    float rl = 1.f / l_i;
#pragma unroll
    for (int mi = 0; mi < 4; ++mi)
#pragma unroll
      for (int r = 0; r < 4; ++r) {
        int hd = mi * 16 + quad * 4 + r;
        attnb[((size_t)(b * SEQ + qg)) * D_MODEL + h * HD + hd] = f2bf(oacc[mi][r] * rl);
      }
  }
}

// ---------------- output projection: (4096x1024) @ (1024x1024) + bias -> fp32 --
__global__ __launch_bounds__(256) void out_gemm_kernel(
    const u16* __restrict__ A, const u16* __restrict__ Bt, const float* __restrict__ bias,
    float* __restrict__ out) {
  __shared__ u16 As[128 * 64];
  __shared__ u16 Bs[128 * 64];
  const int tid = threadIdx.x;
  const int lane = tid & 63, wave = tid >> 6;
  const int wr = (wave >> 1) << 6, wc = (wave & 1) << 6;
  const int lrow = lane & 15, quad = lane >> 4;
  const int lk = quad * 8;
  const int rowA0 = blockIdx.y * 128, rowB0 = blockIdx.x * 128;

  f32x4 acc[4][4] = {};

  for (int k0 = 0; k0 < KDIM; k0 += 64) {
    __syncthreads();
#pragma unroll
    for (int it = 0; it < 4; ++it) {
      int flat = it * 256 + tid;
      int r = flat >> 3, c = (flat & 7) << 3;
      gload16(A + (size_t)(rowA0 + r) * KDIM + k0 + c, As + flat * 8);
      gload16(Bt + (size_t)(rowB0 + r) * KDIM + k0 + c, Bs + flat * 8);
    }
    __syncthreads();
#pragma unroll
    for (int kk = 0; kk < 64; kk += 32) {
      bf16x8 af[4], bfr[4];
#pragma unroll
      for (int mi = 0; mi < 4; ++mi)
        af[mi] = *(const bf16x8*)(As + (wr + mi * 16 + lrow) * 64 + kk + lk);
#pragma unroll
      for (int ni = 0; ni < 4; ++ni)
        bfr[ni] = *(const bf16x8*)(Bs + (wc + ni * 16 + lrow) * 64 + kk + lk);
#pragma unroll
      for (int mi = 0; mi < 4; ++mi)
#pragma unroll
        for (int ni = 0; ni < 4; ++ni)
          acc[mi][ni] = __builtin_amdgcn_mfma_f32_16x16x32_bf16(af[mi], bfr[ni], acc[mi][ni], 0, 0, 0);
    }
  }

#pragma unroll
  for (int ni = 0; ni < 4; ++ni) {
    int col = rowB0 + wc + ni * 16 + lrow;
    float bv = bias[col];
#pragma unroll
    for (int mi = 0; mi < 4; ++mi)
#pragma unroll
      for (int r = 0; r < 4; ++r) {
        int row = rowA0 + wr + mi * 16 + quad * 4 + r;
        out[(size_t)row * D_MODEL + col] = acc[mi][ni][r] + bv;
      }
  }
}

extern "C" void kernel_launch(void* const* d_in, const int* in_sizes, int n_in,
                              void* d_out, int out_size, void* d_ws, size_t ws_size,
                              hipStream_t stream) {
  const float* query = (const float*)d_in[0];
  const float* W_qkv = (const float*)d_in[1];
  const float* b_qkv = (const float*)d_in[2];
  const float* W_out = (const float*)d_in[3];
  const float* b_out = (const float*)d_in[4];
  float* out = (float*)d_out;

  char* ws = (char*)d_ws;
  u16* q_bf   = (u16*)(ws);                 //  8 MB  query bf16 (4096x1024)
  u16* wt_qkv = (u16*)(ws + 8388608);       //  6 MB  W_qkv^T bf16 (3072x1024)
  u16* wt_out = (u16*)(ws + 14680064);      //  2 MB  W_out^T bf16 (1024x1024)
  u16* qbuf   = (u16*)(ws + 16777216);      //  8 MB  q (bh,s,hd) swizzled
  u16* kbuf   = (u16*)(ws + 25165824);      //  8 MB  k (bh,s,hd) swizzled
  u16* vtbuf  = (u16*)(ws + 33554432);      //  8 MB  v^T (bh,hd,s) swizzled
  u16* attnb  = (u16*)(ws + 41943040);      //  8 MB  attn (B,S,D) bf16

  convert_f32_bf16<<<dim3(4096), dim3(256), 0, stream>>>(query, q_bf, ROWS * KDIM / 4);
  transpose_bf16<<<dim3(NQKV / 32, KDIM / 32), dim3(32, 8), 0, stream>>>(W_qkv, wt_qkv, KDIM, NQKV);
  transpose_bf16<<<dim3(D_MODEL / 32, KDIM / 32), dim3(32, 8), 0, stream>>>(W_out, wt_out, KDIM, D_MODEL);
  qkv_gemm_kernel<<<dim3(NQKV / 128, ROWS / 128), dim3(256), 0, stream>>>(q_bf, wt_qkv, b_qkv, qbuf, kbuf, vtbuf);
  flash_kernel<<<dim3(512), dim3(256), 0, stream>>>(qbuf, kbuf, vtbuf, attnb);
  out_gemm_kernel<<<dim3(D_MODEL / 128, ROWS / 128), dim3(256), 0, stream>>>(attnb, wt_out, b_out, out);
}

// Round 3
// 211.296 us; speedup vs baseline: 1.5641x; 1.0362x over previous
//
#include <hip/hip_runtime.h>
#include <stdint.h>

#define D_MODEL 1024
#define NH 16
#define HD 64
#define SEQ 2048
#define BATCH 2
#define ROWS (BATCH * SEQ)   // 4096
#define KDIM 1024
#define NQKV 3072

typedef unsigned short u16;
typedef short bf16x8 __attribute__((ext_vector_type(8)));   // 8 bf16 in 4 VGPRs
typedef short bf16x4 __attribute__((ext_vector_type(4)));   // 4 bf16 in 2 VGPRs
typedef float f32x4 __attribute__((ext_vector_type(4)));

__device__ __forceinline__ u16 f2bf(float f) {
  union { float f; unsigned u; } x; x.f = f;
  unsigned r = x.u + 0x7fff + ((x.u >> 16) & 1);   // RNE
  return (u16)(r >> 16);
}

#ifndef HAVE_MFMA16_1K
#if defined(__has_builtin)
#if __has_builtin(__builtin_amdgcn_mfma_f32_16x16x16bf16_1k)
#define HAVE_MFMA16_1K 1
#endif
#endif
#endif
__device__ __forceinline__ f32x4 mfma16(bf16x4 a, bf16x4 b, f32x4 c) {
#ifdef HAVE_MFMA16_1K
  return __builtin_amdgcn_mfma_f32_16x16x16bf16_1k(a, b, c, 0, 0, 0);
#else
  bf16x8 a8 = {a[0], a[1], a[2], a[3], 0, 0, 0, 0};
  bf16x8 b8 = {b[0], b[1], b[2], b[3], 0, 0, 0, 0};
  return __builtin_amdgcn_mfma_f32_16x16x32_bf16(a8, b8, c, 0, 0, 0);
#endif
}

// async global->LDS, 16B/lane. LDS dst is wave-uniform base + lane*16;
// global SOURCE address is per-lane arbitrary (16B contiguous) -> swizzle there.
__device__ __forceinline__ void gload16(const u16* g, u16* l) {
  __builtin_amdgcn_global_load_lds(
      (const __attribute__((address_space(1))) unsigned int*)g,
      (__attribute__((address_space(3))) unsigned int*)l, 16, 0, 0);
}

// ---------------- fused prep: convert query, transpose weights, rope table ----
__global__ void prep_kernel(const float* __restrict__ query, u16* __restrict__ q_bf,
                            const float* __restrict__ W_qkv, u16* __restrict__ wt_qkv,
                            const float* __restrict__ W_out, u16* __restrict__ wt_out,
                            float2* __restrict__ rope_tab) {
  __shared__ float tile[32][33];
  const int blk = blockIdx.x, tid = threadIdx.x;
  if (blk < 4096) {                       // query fp32 -> bf16 (float4/ushort4)
    int i = blk * 256 + tid;
    float4 v = ((const float4*)query)[i];
    ushort4 o;
    o.x = f2bf(v.x); o.y = f2bf(v.y); o.z = f2bf(v.z); o.w = f2bf(v.w);
    ((ushort4*)q_bf)[i] = o;
  } else if (blk < 8192) {                // W transpose+convert (32x32 tiles)
    const float* W; u16* Wt; int N, t;
    if (blk < 7168) { W = W_qkv; Wt = wt_qkv; N = NQKV; t = blk - 4096; }
    else            { W = W_out; Wt = wt_out; N = D_MODEL; t = blk - 7168; }
    int nb = N / 32;
    int c0 = (t % nb) * 32, r0 = (t / nb) * 32;
    int tx = tid & 31, ty = tid >> 5;     // (32, 8)
    for (int i = ty; i < 32; i += 8)
      tile[i][tx] = W[(size_t)(r0 + i) * N + c0 + tx];
    __syncthreads();
    for (int i = ty; i < 32; i += 8)
      Wt[(size_t)(c0 + i) * KDIM + r0 + tx] = f2bf(tile[tx][i]);
  } else {                                // rope table: tab[s*32+f] = (cos, sin)
    int i = (blk - 8192) * 256 + tid;     // 65536 entries
    int s = i >> 5, f = i & 31;
    float inv = __expf(-(float)f * 0.28782313662425572f);  // ln(1e4)/32
    float ang = (float)s * inv;
    rope_tab[i] = make_float2(cosf(ang), sinf(ang));
  }
}

// ---------------- QKV GEMM + bias + table-RoPE + coalesced scatter ----------------
// outputs PLAIN layouts: qb/kb[bh][s][hd], vtb[bh][hd][s]
__global__ __launch_bounds__(256) void qkv_gemm_kernel(
    const u16* __restrict__ A, const u16* __restrict__ Bt, const float* __restrict__ bias,
    const float2* __restrict__ rope_tab,
    u16* __restrict__ qb, u16* __restrict__ kb, u16* __restrict__ vtb) {
  __shared__ u16 smem[16384];            // As | Bs, reused by epilogue transpose
  u16* As = smem;
  u16* Bs = smem + 8192;
  const int tid = threadIdx.x;
  const int lane = tid & 63, wave = tid >> 6;
  const int wr = (wave >> 1) << 6, wc = (wave & 1) << 6;
  const int lrow = lane & 15, quad = lane >> 4;
  const int lk = quad * 8;
  const int rowA0 = blockIdx.y * 128, rowB0 = blockIdx.x * 128;

  f32x4 acc[4][4] = {};

  for (int k0 = 0; k0 < KDIM; k0 += 64) {
    __syncthreads();
#pragma unroll
    for (int it = 0; it < 4; ++it) {
      int flat = it * 256 + tid;
      int r = flat >> 3, c = (flat & 7) << 3;
      gload16(A + (size_t)(rowA0 + r) * KDIM + k0 + c, As + flat * 8);
      gload16(Bt + (size_t)(rowB0 + r) * KDIM + k0 + c, Bs + flat * 8);
    }
    __syncthreads();
#pragma unroll
    for (int kk = 0; kk < 64; kk += 32) {
      bf16x8 af[4], bfr[4];
#pragma unroll
      for (int mi = 0; mi < 4; ++mi)
        af[mi] = *(const bf16x8*)(As + (wr + mi * 16 + lrow) * 64 + kk + lk);
#pragma unroll
      for (int ni = 0; ni < 4; ++ni)
        bfr[ni] = *(const bf16x8*)(Bs + (wc + ni * 16 + lrow) * 64 + kk + lk);
#pragma unroll
      for (int mi = 0; mi < 4; ++mi)
#pragma unroll
        for (int ni = 0; ni < 4; ++ni)
          acc[mi][ni] = __builtin_amdgcn_mfma_f32_16x16x32_bf16(af[mi], bfr[ni], acc[mi][ni], 0, 0, 0);
    }
  }
  __syncthreads();   // all waves done with As/Bs before epilogue reuses smem

  const int col0 = rowB0 + wc;           // 64-aligned -> one head-slab per wave
  const int which = col0 >> 10;          // 0=q 1=k 2=v (wave-uniform)
  const int h = (col0 & 1023) >> 6;
  const int b = rowA0 >> 11;
  const int sbase = (rowA0 & 2047) + wr; // slab rows all in batch b

#pragma unroll
  for (int ni = 0; ni < 4; ++ni) {
    float bv = bias[col0 + ni * 16 + lrow];
#pragma unroll
    for (int mi = 0; mi < 4; ++mi)
#pragma unroll
      for (int r = 0; r < 4; ++r) acc[mi][ni][r] += bv;
  }

  if (which < 2) {
    // RoPE: pairs (hd, hd+32) = (ni=p, ni=p+2), same lane; table lookups
#pragma unroll
    for (int p = 0; p < 2; ++p) {
#pragma unroll
      for (int mi = 0; mi < 4; ++mi)
#pragma unroll
        for (int r = 0; r < 4; ++r) {
          int sg = sbase + mi * 16 + quad * 4 + r;
          float2 cs = rope_tab[sg * 32 + p * 16 + lrow];
          float x1 = acc[mi][p][r], x2 = acc[mi][p + 2][r];
          acc[mi][p][r]     = x1 * cs.x - x2 * cs.y;
          acc[mi][p + 2][r] = x2 * cs.x + x1 * cs.y;
        }
    }
    // in-wave LDS transpose (xor-swizzled cols), then coalesced 16B stores
    u16* myt = smem + wave * 4096;       // 64 x 64 bf16 slab
#pragma unroll
    for (int ni = 0; ni < 4; ++ni) {
      int hd = ni * 16 + lrow;
#pragma unroll
      for (int mi = 0; mi < 4; ++mi)
#pragma unroll
        for (int r = 0; r < 4; ++r) {
          int sl = mi * 16 + quad * 4 + r;
          int pos = ((((hd >> 3) ^ (sl & 7)) << 3)) | (hd & 7);
          myt[sl * 64 + pos] = f2bf(acc[mi][ni][r]);
        }
    }
    u16* dst = ((which == 0) ? qb : kb) + ((size_t)(b * NH + h) * SEQ + sbase) * HD;
    const int a = lane >> 3, pb = lane & 7;
#pragma unroll
    for (int it = 0; it < 8; ++it) {
      int sl = it * 8 + a;
      bf16x8 v = *(const bf16x8*)(myt + sl * 64 + (pb << 3));
      *(bf16x8*)(dst + sl * 64 + ((pb ^ a) << 3)) = v;   // undo swizzle -> plain
    }
  } else {
    // V^T: C-layout r-quad = 4 consecutive s at fixed hd -> packed 8B stores
    u16* dst = vtb + (size_t)(b * NH + h) * HD * SEQ;
#pragma unroll
    for (int ni = 0; ni < 4; ++ni) {
      int hd = ni * 16 + lrow;
#pragma unroll
      for (int mi = 0; mi < 4; ++mi) {
        ushort4 pk;
        pk.x = f2bf(acc[mi][ni][0]); pk.y = f2bf(acc[mi][ni][1]);
        pk.z = f2bf(acc[mi][ni][2]); pk.w = f2bf(acc[mi][ni][3]);
        *(ushort4*)(dst + (size_t)hd * SEQ + sbase + mi * 16 + quad * 4) = pk;
      }
    }
  }
}

// ---------------- causal flash attention v3 ----------------
// 1024 blocks, one 64-row q-tile each (heavy tiles first), 64-key K/V tiles,
// double-buffered, 32 KB LDS -> ~4 blocks/CU. Q fragments live in registers.
// Bank swizzles applied via global_load_lds SOURCE addresses (plain layouts).
__global__ __launch_bounds__(256, 4) void flash_kernel(
    const u16* __restrict__ qb, const u16* __restrict__ kb,
    const u16* __restrict__ vtb, u16* __restrict__ attnb) {
  __shared__ u16 Ks[2][64 * 64];       // 16 KB
  __shared__ u16 Vts[2][64 * 64];      // 16 KB (hd x key)

  const int tid = threadIdx.x, lane = tid & 63, wave = tid >> 6;
  const int lrow = lane & 15, quad = lane >> 4;
  const int id = blockIdx.x;
  const int tile = 31 - (id >> 5);     // descending: heavy blocks dispatch first
  const int bh = id & 31;
  const int b = bh >> 4, h = bh & 15;

  const u16* qp = qb + (size_t)bh * SEQ * HD;
  const u16* kp = kb + (size_t)bh * SEQ * HD;
  const u16* vp = vtb + (size_t)bh * HD * SEQ;

  const int qg = tile * 64 + wave * 16 + lrow;   // this lane's q row
  // Q B-fragments straight to registers (k = hc*32 + quad*8 + j)
  bf16x8 bq0 = *(const bf16x8*)(qp + (size_t)qg * HD + quad * 8);
  bf16x8 bq1 = *(const bf16x8*)(qp + (size_t)qg * HD + 32 + quad * 8);

#pragma unroll
  for (int it = 0; it < 2; ++it) {     // stage K/V tile 0 into buf 0
    int f = it * 256 + tid;
    int r = f >> 3, c = f & 7;
    gload16(kp + (size_t)r * HD + (((c ^ (r & 7)) << 3)), Ks[0] + f * 8);
    gload16(vp + (size_t)r * SEQ + ((c ^ (r & 7)) << 3), Vts[0] + f * 8);
  }

  float m_i = -3.0e38f, l_i = 0.f;
  f32x4 oacc[4] = {};
  const float kS = 0.18033688011112042f;   // log2(e)/sqrt(64)
  const int kmax = tile;
  const int sw = lrow & 7;

  for (int kt = 0; kt <= kmax; ++kt) {
    const int cur = kt & 1, nxt = cur ^ 1;
    __syncthreads();                   // drains cur staging; guards LDS reuse
    if (kt < kmax) {                   // async prefetch next tile over compute
#pragma unroll
      for (int it = 0; it < 2; ++it) {
        int f = it * 256 + tid;
        int r = f >> 3, c = f & 7;
        gload16(kp + (size_t)((kt + 1) * 64 + r) * HD + ((c ^ (r & 7)) << 3),
                Ks[nxt] + f * 8);
        gload16(vp + (size_t)r * SEQ + (kt + 1) * 64 + ((c ^ (r & 7)) << 3),
                Vts[nxt] + f * 8);
      }
    }

    // S^T = K·Q^T : lane holds S^T[key = ki*16+quad*4+r][q = qg]
    f32x4 sc[4] = {};
#pragma unroll
    for (int hc = 0; hc < 2; ++hc) {
      bf16x8 bq = hc ? bq1 : bq0;
#pragma unroll
      for (int ki = 0; ki < 4; ++ki) {
        bf16x8 ak = *(const bf16x8*)(Ks[cur] + (ki * 16 + lrow) * 64 +
                                     (((hc * 4 + quad) ^ sw) << 3));
        sc[ki] = __builtin_amdgcn_mfma_f32_16x16x32_bf16(ak, bq, sc[ki], 0, 0, 0);
      }
    }

    if (kt == kmax) {                  // causal mask (diagonal tile only)
#pragma unroll
      for (int ki = 0; ki < 4; ++ki)
#pragma unroll
        for (int r = 0; r < 4; ++r)
          if (kt * 64 + ki * 16 + quad * 4 + r > qg) sc[ki][r] = -1e30f;
    }

    // online softmax: 16 in-lane values + 2 shfls
    float mx = sc[0][0];
#pragma unroll
    for (int ki = 0; ki < 4; ++ki)
#pragma unroll
      for (int r = 0; r < 4; ++r) mx = fmaxf(mx, sc[ki][r]);
    mx = fmaxf(mx, __shfl_xor(mx, 16));
    mx = fmaxf(mx, __shfl_xor(mx, 32));
    float mnew = fmaxf(m_i, mx);
    float al = exp2f((m_i - mnew) * kS);
    float sum = 0.f;
#pragma unroll
    for (int ki = 0; ki < 4; ++ki)
#pragma unroll
      for (int r = 0; r < 4; ++r) {
        float p = exp2f((sc[ki][r] - mnew) * kS);
        sc[ki][r] = p;
        sum += p;
      }
    sum += __shfl_xor(sum, 16);
    sum += __shfl_xor(sum, 32);
    l_i = l_i * al + sum;
    m_i = mnew;
#pragma unroll
    for (int mi = 0; mi < 4; ++mi) oacc[mi] *= al;

    // P^T: C-layout rows(=keys, quad*4+r) ARE the K=16 B-fragment layout
    bf16x4 pf[4];
#pragma unroll
    for (int ki = 0; ki < 4; ++ki) {
      bf16x4 t;
      t[0] = (short)f2bf(sc[ki][0]); t[1] = (short)f2bf(sc[ki][1]);
      t[2] = (short)f2bf(sc[ki][2]); t[3] = (short)f2bf(sc[ki][3]);
      pf[ki] = t;
    }

    // O^T += V^T·P^T  (A-frag: keys ki*16+quad*4..+3 from swizzled Vts)
#pragma unroll
    for (int mi = 0; mi < 4; ++mi) {
      int vrow = (mi * 16 + lrow) * 64;
#pragma unroll
      for (int ki = 0; ki < 4; ++ki) {
        bf16x4 av = *(const bf16x4*)(Vts[cur] + vrow +
                                     ((((ki * 2 + (quad >> 1)) ^ sw) << 3) | ((quad & 1) << 2)));
        oacc[mi] = mfma16(av, pf[ki], oacc[mi]);
      }
    }
  }

  // epilogue: lane owns q=qg entirely; pack 4 consecutive hd -> 8B stores
  float rl = 1.f / l_i;
  u16* op = attnb + ((size_t)(b * SEQ + qg)) * D_MODEL + h * HD;
#pragma unroll
  for (int mi = 0; mi < 4; ++mi) {
    ushort4 pk;
    pk.x = f2bf(oacc[mi][0] * rl); pk.y = f2bf(oacc[mi][1] * rl);
    pk.z = f2bf(oacc[mi][2] * rl); pk.w = f2bf(oacc[mi][3] * rl);
    *(ushort4*)(op + mi * 16 + quad * 4) = pk;
  }
}

// ---------------- output projection: 128x64 tiles -> 512 blocks ----------------
__global__ __launch_bounds__(256) void out_gemm_kernel(
    const u16* __restrict__ A, const u16* __restrict__ Bt, const float* __restrict__ bias,
    float* __restrict__ out) {
  __shared__ u16 smem[128 * 64 + 64 * 64];
  u16* As = smem;
  u16* Bs = smem + 128 * 64;
  const int tid = threadIdx.x;
  const int lane = tid & 63, wave = tid >> 6;
  const int lrow = lane & 15, quad = lane >> 4;
  const int wr = wave * 32;
  const int rowA0 = blockIdx.y * 128, colB0 = blockIdx.x * 64;

  f32x4 acc[2][4] = {};

  for (int k0 = 0; k0 < KDIM; k0 += 64) {
    __syncthreads();
#pragma unroll
    for (int it = 0; it < 4; ++it) {
      int f = it * 256 + tid;
      gload16(A + (size_t)(rowA0 + (f >> 3)) * KDIM + k0 + ((f & 7) << 3), As + f * 8);
    }
#pragma unroll
    for (int it = 0; it < 2; ++it) {
      int f = it * 256 + tid;
      gload16(Bt + (size_t)(colB0 + (f >> 3)) * KDIM + k0 + ((f & 7) << 3), Bs + f * 8);
    }
    __syncthreads();
#pragma unroll
    for (int kk = 0; kk < 64; kk += 32) {
      bf16x8 af[2], bfr[4];
#pragma unroll
      for (int mi = 0; mi < 2; ++mi)
        af[mi] = *(const bf16x8*)(As + (wr + mi * 16 + lrow) * 64 + kk + quad * 8);
#pragma unroll
      for (int ni = 0; ni < 4; ++ni)
        bfr[ni] = *(const bf16x8*)(Bs + (ni * 16 + lrow) * 64 + kk + quad * 8);
#pragma unroll
      for (int mi = 0; mi < 2; ++mi)
#pragma unroll
        for (int ni = 0; ni < 4; ++ni)
          acc[mi][ni] = __builtin_amdgcn_mfma_f32_16x16x32_bf16(af[mi], bfr[ni], acc[mi][ni], 0, 0, 0);
    }
  }

#pragma unroll
  for (int ni = 0; ni < 4; ++ni) {
    int col = colB0 + ni * 16 + lrow;
    float bv = bias[col];
#pragma unroll
    for (int mi = 0; mi < 2; ++mi)
#pragma unroll
      for (int r = 0; r < 4; ++r) {
        int row = rowA0 + wr + mi * 16 + quad * 4 + r;
        out[(size_t)row * D_MODEL + col] = acc[mi][ni][r] + bv;
      }
  }
}

extern "C" void kernel_launch(void* const* d_in, const int* in_sizes, int n_in,
                              void* d_out, int out_size, void* d_ws, size_t ws_size,
                              hipStream_t stream) {
  const float* query = (const float*)d_in[0];
  const float* W_qkv = (const float*)d_in[1];
  const float* b_qkv = (const float*)d_in[2];
  const float* W_out = (const float*)d_in[3];
  const float* b_out = (const float*)d_in[4];
  float* out = (float*)d_out;

  char* ws = (char*)d_ws;
  u16* q_bf    = (u16*)(ws);                 //  8 MB  query bf16 (4096x1024)
  u16* wt_qkv  = (u16*)(ws + 8388608);       //  6 MB  W_qkv^T bf16
  u16* wt_out  = (u16*)(ws + 14680064);      //  2 MB  W_out^T bf16
  u16* qbuf    = (u16*)(ws + 16777216);      //  8 MB  q (bh,s,hd) plain
  u16* kbuf    = (u16*)(ws + 25165824);      //  8 MB  k (bh,s,hd) plain
  u16* vtbuf   = (u16*)(ws + 33554432);      //  8 MB  v^T (bh,hd,s) plain
  u16* attnb   = (u16*)(ws + 41943040);      //  8 MB  attn (B,S,D) bf16
  float2* rope = (float2*)(ws + 50331648);   // 512 KB rope table (s,freq)

  prep_kernel<<<dim3(8448), dim3(256), 0, stream>>>(query, q_bf, W_qkv, wt_qkv, W_out, wt_out, rope);
  qkv_gemm_kernel<<<dim3(NQKV / 128, ROWS / 128), dim3(256), 0, stream>>>(
      q_bf, wt_qkv, b_qkv, rope, qbuf, kbuf, vtbuf);
  flash_kernel<<<dim3(1024), dim3(256), 0, stream>>>(qbuf, kbuf, vtbuf, attnb);
  out_gemm_kernel<<<dim3(D_MODEL / 64, ROWS / 128), dim3(256), 0, stream>>>(attnb, wt_out, b_out, out);
}